// Round 1
// baseline (77.041 us; speedup 1.0000x reference)
//
#include <hip/hip_runtime.h>
#include <math.h>

#define N_ROWS 8192   // SIZE
#define N_COLS 1024   // M
#define CHUNKS 256
#define ROWS_PER_CHUNK (N_ROWS / CHUNKS)  // 32

// Pass 1: per-(chunk, column) partial max and sum(exp(x - max)).
// Grid: CHUNKS blocks x 1024 threads (thread j = column j).
__global__ __launch_bounds__(1024) void colstats_part(
    const float* __restrict__ x, float* __restrict__ pm, float* __restrict__ ps) {
    const int c = blockIdx.x;
    const int j = threadIdx.x;
    const int r0 = c * ROWS_PER_CHUNK;
    float v[ROWS_PER_CHUNK];
#pragma unroll
    for (int k = 0; k < ROWS_PER_CHUNK; ++k)
        v[k] = x[(size_t)(r0 + k) * N_COLS + j];
    float m = v[0];
#pragma unroll
    for (int k = 1; k < ROWS_PER_CHUNK; ++k) m = fmaxf(m, v[k]);
    float s = 0.f;
#pragma unroll
    for (int k = 0; k < ROWS_PER_CHUNK; ++k) s += __expf(v[k] - m);
    pm[c * N_COLS + j] = m;
    ps[c * N_COLS + j] = s;
}

// Pass 2: merge chunk partials per column -> mB[j], T[j].
// Grid: 4 blocks x 256 threads (global thread j = column j).
__global__ void colstats_merge(
    const float* __restrict__ pm, const float* __restrict__ ps,
    float* __restrict__ mB, float* __restrict__ T) {
    const int j = blockIdx.x * blockDim.x + threadIdx.x;
    float m = -INFINITY;
    for (int c = 0; c < CHUNKS; ++c) m = fmaxf(m, pm[c * N_COLS + j]);
    float s = 0.f;
    for (int c = 0; c < CHUNKS; ++c) s += ps[c * N_COLS + j] * __expf(pm[c * N_COLS + j] - m);
    mB[j] = m;
    T[j]  = s;
}

// Pass 3: elementwise finalize, float4 over columns.
// out[i,j] = rA + mB[j] + log( exp(diag[i]-rA)*e + exp(-rA)*(T[j]-e) ),
//   e = exp(x[i,j]-mB[j]), rA = max(diag[i], 0).
__global__ void finalize(
    const float* __restrict__ x, const float* __restrict__ diag,
    const float* __restrict__ mB, const float* __restrict__ T,
    float* __restrict__ out) {
    const int gid = blockIdx.x * blockDim.x + threadIdx.x;  // vec4 index
    const int i  = gid >> 8;        // N_COLS/4 = 256 vec4 per row
    const int jv = gid & 255;
    const size_t off = (size_t)i * N_COLS + (size_t)jv * 4;

    const float4 xv = *reinterpret_cast<const float4*>(x + off);
    const float4 mv = *reinterpret_cast<const float4*>(mB + (size_t)jv * 4);
    const float4 Tv = *reinterpret_cast<const float4*>(T  + (size_t)jv * 4);

    const float di  = diag[i];
    const float rA  = fmaxf(di, 0.f);
    const float edd = __expf(di - rA);   // exp(diag[i] - rA)
    const float er  = __expf(-rA);       // exp(-rA)

    float4 o;
    {
        const float e = __expf(xv.x - mv.x);
        o.x = rA + mv.x + __logf(edd * e + er * (Tv.x - e));
    }
    {
        const float e = __expf(xv.y - mv.y);
        o.y = rA + mv.y + __logf(edd * e + er * (Tv.y - e));
    }
    {
        const float e = __expf(xv.z - mv.z);
        o.z = rA + mv.z + __logf(edd * e + er * (Tv.z - e));
    }
    {
        const float e = __expf(xv.w - mv.w);
        o.w = rA + mv.w + __logf(edd * e + er * (Tv.w - e));
    }
    *reinterpret_cast<float4*>(out + off) = o;
}

extern "C" void kernel_launch(void* const* d_in, const int* in_sizes, int n_in,
                              void* d_out, int out_size, void* d_ws, size_t ws_size,
                              hipStream_t stream) {
    const float* x    = (const float*)d_in[0];   // [8192, 1024] f32
    const float* diag = (const float*)d_in[1];   // [8192] f32
    float* out = (float*)d_out;                  // [8192, 1024] f32
    float* ws  = (float*)d_ws;

    float* pm = ws;                      // CHUNKS * N_COLS
    float* ps = pm + CHUNKS * N_COLS;    // CHUNKS * N_COLS
    float* mB = ps + CHUNKS * N_COLS;    // N_COLS
    float* T  = mB + N_COLS;             // N_COLS
    // total ws use: (2*256*1024 + 2048) * 4 B ~= 2.06 MB

    colstats_part<<<CHUNKS, 1024, 0, stream>>>(x, pm, ps);
    colstats_merge<<<N_COLS / 256, 256, 0, stream>>>(pm, ps, mB, T);
    const int vec4_total = N_ROWS * (N_COLS / 4);          // 2,097,152
    finalize<<<vec4_total / 256, 256, 0, stream>>>(x, diag, mB, T, out);
}

// Round 2
// 29.070 us; speedup vs baseline: 2.6502x; 2.6502x over previous
//
#include <hip/hip_runtime.h>
#include <math.h>

#define N_ROWS 8192   // SIZE
#define N_COLS 1024   // M
#define CHUNKS 256
#define ROWS_PER_CHUNK (N_ROWS / CHUNKS)  // 32

// Pass 1: per-(chunk, column) partial max and sum(exp(x - max)).
// Grid: CHUNKS blocks x 1024 threads (thread j = column j).
__global__ __launch_bounds__(1024) void colstats_part(
    const float* __restrict__ x, float* __restrict__ pm, float* __restrict__ ps) {
    const int c = blockIdx.x;
    const int j = threadIdx.x;
    const int r0 = c * ROWS_PER_CHUNK;
    float v[ROWS_PER_CHUNK];
#pragma unroll
    for (int k = 0; k < ROWS_PER_CHUNK; ++k)
        v[k] = x[(size_t)(r0 + k) * N_COLS + j];
    float m = v[0];
#pragma unroll
    for (int k = 1; k < ROWS_PER_CHUNK; ++k) m = fmaxf(m, v[k]);
    float s = 0.f;
#pragma unroll
    for (int k = 0; k < ROWS_PER_CHUNK; ++k) s += __expf(v[k] - m);
    pm[c * N_COLS + j] = m;
    ps[c * N_COLS + j] = s;
}

// Pass 2: merge chunk partials per column -> mB[j], T[j].
// Grid: N_COLS blocks x CHUNKS threads. Thread c of block j owns chunk c.
__global__ __launch_bounds__(256) void colstats_merge(
    const float* __restrict__ pm, const float* __restrict__ ps,
    float* __restrict__ mB, float* __restrict__ T) {
    const int j = blockIdx.x;
    const int c = threadIdx.x;
    const int wid  = c >> 6;       // wave id (0..3)
    const int lane = c & 63;

    __shared__ float red[4];

    const float m = pm[(size_t)c * N_COLS + j];   // transposed-in-index read; L2/L3 hot
    const float s = ps[(size_t)c * N_COLS + j];

    // --- global max across 256 threads ---
    float mm = m;
#pragma unroll
    for (int off = 32; off; off >>= 1) mm = fmaxf(mm, __shfl_down(mm, off));
    if (lane == 0) red[wid] = mm;
    __syncthreads();
    const float M = fmaxf(fmaxf(red[0], red[1]), fmaxf(red[2], red[3]));
    __syncthreads();

    // --- sum of s_c * exp(m_c - M) ---
    float t = s * __expf(m - M);
#pragma unroll
    for (int off = 32; off; off >>= 1) t += __shfl_down(t, off);
    if (lane == 0) red[wid] = t;
    __syncthreads();
    if (c == 0) {
        mB[j] = M;
        T[j]  = red[0] + red[1] + red[2] + red[3];
    }
}

// Pass 3: elementwise finalize, float4 over columns.
// out[i,j] = rA + mB[j] + log( exp(diag[i]-rA)*e + exp(-rA)*(T[j]-e) ),
//   e = exp(x[i,j]-mB[j]), rA = max(diag[i], 0).
__global__ void finalize(
    const float* __restrict__ x, const float* __restrict__ diag,
    const float* __restrict__ mB, const float* __restrict__ T,
    float* __restrict__ out) {
    const int gid = blockIdx.x * blockDim.x + threadIdx.x;  // vec4 index
    const int i  = gid >> 8;        // N_COLS/4 = 256 vec4 per row
    const int jv = gid & 255;
    const size_t off = (size_t)i * N_COLS + (size_t)jv * 4;

    const float4 xv = *reinterpret_cast<const float4*>(x + off);
    const float4 mv = *reinterpret_cast<const float4*>(mB + (size_t)jv * 4);
    const float4 Tv = *reinterpret_cast<const float4*>(T  + (size_t)jv * 4);

    const float di  = diag[i];
    const float rA  = fmaxf(di, 0.f);
    const float edd = __expf(di - rA);   // exp(diag[i] - rA)
    const float er  = __expf(-rA);       // exp(-rA)

    float4 o;
    {
        const float e = __expf(xv.x - mv.x);
        o.x = rA + mv.x + __logf(edd * e + er * (Tv.x - e));
    }
    {
        const float e = __expf(xv.y - mv.y);
        o.y = rA + mv.y + __logf(edd * e + er * (Tv.y - e));
    }
    {
        const float e = __expf(xv.z - mv.z);
        o.z = rA + mv.z + __logf(edd * e + er * (Tv.z - e));
    }
    {
        const float e = __expf(xv.w - mv.w);
        o.w = rA + mv.w + __logf(edd * e + er * (Tv.w - e));
    }
    *reinterpret_cast<float4*>(out + off) = o;
}

extern "C" void kernel_launch(void* const* d_in, const int* in_sizes, int n_in,
                              void* d_out, int out_size, void* d_ws, size_t ws_size,
                              hipStream_t stream) {
    const float* x    = (const float*)d_in[0];   // [8192, 1024] f32
    const float* diag = (const float*)d_in[1];   // [8192] f32
    float* out = (float*)d_out;                  // [8192, 1024] f32
    float* ws  = (float*)d_ws;

    float* pm = ws;                      // CHUNKS * N_COLS
    float* ps = pm + CHUNKS * N_COLS;    // CHUNKS * N_COLS
    float* mB = ps + CHUNKS * N_COLS;    // N_COLS
    float* T  = mB + N_COLS;             // N_COLS
    // total ws use: (2*256*1024 + 2048) * 4 B ~= 2.06 MB

    colstats_part<<<CHUNKS, 1024, 0, stream>>>(x, pm, ps);
    colstats_merge<<<N_COLS, CHUNKS, 0, stream>>>(pm, ps, mB, T);
    const int vec4_total = N_ROWS * (N_COLS / 4);          // 2,097,152
    finalize<<<vec4_total / 256, 256, 0, stream>>>(x, diag, mB, T, out);
}